// Round 10
// baseline (203.717 us; speedup 1.0000x reference)
//
#include <hip/hip_runtime.h>

// World model (rounds 0-9): ALL inputs fp32, output buffer fp32.
// Fixed harness work ~150 us; controllable: k1 ~5 us (R8 version, R9's
// "coalesced" variant regressed), k2 ~35-40 us vs ~16-22 us floor.
// R10: k2 -> 1024 blocks x 256 thr (finer tail), mask/dir in LDS (frees VGPRs),
// explicit 2-stage register pipeline on the 9-load bundle. k1 = R8 verbatim.

#define B_ 4
#define N_ 128
#define D_ 128

typedef __attribute__((ext_vector_type(4))) float float4v;

// Static scratch: x = Dense2(GLU(Dense1(RMSNorm(q)))) as (B,N,3D) fp32.
__device__ __align__(16) float g_x[B_ * N_ * 3 * D_];

__device__ __forceinline__ float sigm(float x) { return 1.0f / (1.0f + __expf(-x)); }

// ---------------- Kernel 1: RMSNorm + GLU MLP -> g_x (R8 verbatim) --------------
__global__ __launch_bounds__(256) void k1_mlp(
        const float* __restrict__ q, const float* __restrict__ norm_w,
        const float* __restrict__ W1, const float* __restrict__ b1,
        const float* __restrict__ W2, const float* __restrict__ b2) {
    const int row = blockIdx.x;   // 0 .. B*N-1
    const int t   = threadIdx.x;  // 0 .. 255

    __shared__ __align__(16) float hbuf[D_];
    __shared__ __align__(16) float h2buf[D_];
    __shared__ float ybuf[2 * D_];
    __shared__ float red4[4];

    float v  = (t < D_) ? q[(size_t)row * D_ + t] : 0.0f;
    float ss = v * v;
    #pragma unroll
    for (int off = 32; off > 0; off >>= 1) ss += __shfl_down(ss, off);
    if ((t & 63) == 0) red4[t >> 6] = ss;
    __syncthreads();
    float var   = (red4[0] + red4[1] + red4[2] + red4[3]) * (1.0f / D_);
    float scale = rsqrtf(var + 1e-6f);
    if (t < D_) hbuf[t] = v * scale * (1.0f + norm_w[t]);
    __syncthreads();

    float y = b1[t];
    const float4v* wr = (const float4v*)(W1 + (size_t)t * D_);
    #pragma unroll 8
    for (int c = 0; c < D_ / 4; ++c) {
        float4v w4 = wr[c];
        float4v h4 = *(const float4v*)&hbuf[4 * c];
        y += w4.x * h4.x + w4.y * h4.y + w4.z * h4.z + w4.w * h4.w;
    }
    ybuf[t] = y;
    __syncthreads();
    if (t < D_) {
        float a = ybuf[t], g = ybuf[D_ + t];
        h2buf[t] = a * sigm(a) * sigm(g);
    }
    __syncthreads();

    float x0 = b2[t];
    float x1 = (t < D_) ? b2[2 * D_ + t] : 0.0f;
    const float4v* w0 = (const float4v*)(W2 + (size_t)t * D_);
    const float4v* w1 = (const float4v*)(W2 + (size_t)(2 * D_ + (t & (D_ - 1))) * D_);
    #pragma unroll 8
    for (int c = 0; c < D_ / 4; ++c) {
        float4v h4 = *(const float4v*)&h2buf[4 * c];
        float4v a4 = w0[c];
        x0 += a4.x * h4.x + a4.y * h4.y + a4.z * h4.z + a4.w * h4.w;
        if (t < D_) {
            float4v b4 = w1[c];
            x1 += b4.x * h4.x + b4.y * h4.y + b4.z * h4.z + b4.w * h4.w;
        }
    }
    float* xr = g_x + (size_t)row * (3 * D_);
    xr[t] = x0;
    if (t < D_) xr[2 * D_ + t] = x1;
}

// ---------------- Kernel 2: pairwise reduce over j, fused residual epilogue ------
// block = (b, i, channel-half h): 1024 blocks x 256 threads (4 blocks/CU).
// 256 threads = 16 j-slots x 16 channel-quads (64 ch per block).
// mask/dir staged in LDS; explicit 2-stage register pipeline on the 9 loads.
__global__ __launch_bounds__(256, 4) void k2_pair(
        const float* __restrict__ q, const float* __restrict__ mu,
        const float* __restrict__ Wij, const float* __restrict__ dir,
        const float* __restrict__ mask, float* __restrict__ out) {
    const int blk  = blockIdx.x;
    const int bi   = blk >> 1;         // b*N + i
    const int h    = blk & 1;          // channel half
    const int b    = bi >> 7;
    const int t    = threadIdx.x;      // 0..255
    const int quad = t & 15;           // channel quad within half (16 quads = 64 ch)
    const int js   = t >> 4;           // j-slot 0..15
    const int choff = h * 64 + 4 * quad;

    const float* Wb  = Wij  + (size_t)bi * (N_ * 3 * D_);
    const float* mub = mu   + (size_t)b * (N_ * 3 * D_);
    const float* xb  = g_x  + (size_t)b * (N_ * 3 * D_);

    // stage mask (128) + dir (384) into LDS once per block
    __shared__ float smsk[N_];
    __shared__ float sdir[3 * N_];
    {
        const float* mb = mask + (size_t)bi * N_;
        const float* db = dir  + (size_t)bi * (N_ * 3);
        if (t < N_) smsk[t] = mb[t];
        for (int idx = t; idx < 3 * N_; idx += 256) sdir[idx] = db[idx];
    }
    __syncthreads();

    float4v aq = {0.f, 0.f, 0.f, 0.f};
    float4v a0 = {0.f, 0.f, 0.f, 0.f};
    float4v a1 = {0.f, 0.f, 0.f, 0.f};
    float4v a2 = {0.f, 0.f, 0.f, 0.f};

    // 2-stage register pipeline over 8 iterations (j = it*16 + js)
    float4v wqA, wRA, wmA, xqA, xRA, xmA, u0A, u1A, u2A;
    float4v wqB, wRB, wmB, xqB, xRB, xmB, u0B, u1B, u2B;

    {
        const size_t base = (size_t)js * (3 * D_) + choff;
        wqA = __builtin_nontemporal_load((const float4v*)(Wb + base));
        wRA = __builtin_nontemporal_load((const float4v*)(Wb + base + D_));
        wmA = __builtin_nontemporal_load((const float4v*)(Wb + base + 2 * D_));
        xqA = *(const float4v*)(xb + base);
        xRA = *(const float4v*)(xb + base + D_);
        xmA = *(const float4v*)(xb + base + 2 * D_);
        u0A = *(const float4v*)(mub + base);
        u1A = *(const float4v*)(mub + base + D_);
        u2A = *(const float4v*)(mub + base + 2 * D_);
    }

    #pragma unroll
    for (int it = 0; it < 8; ++it) {
        if (it < 7) {   // prefetch next iteration before consuming current
            const int jn = (it + 1) * 16 + js;
            const size_t base = (size_t)jn * (3 * D_) + choff;
            wqB = __builtin_nontemporal_load((const float4v*)(Wb + base));
            wRB = __builtin_nontemporal_load((const float4v*)(Wb + base + D_));
            wmB = __builtin_nontemporal_load((const float4v*)(Wb + base + 2 * D_));
            xqB = *(const float4v*)(xb + base);
            xRB = *(const float4v*)(xb + base + D_);
            xmB = *(const float4v*)(xb + base + 2 * D_);
            u0B = *(const float4v*)(mub + base);
            u1B = *(const float4v*)(mub + base + D_);
            u2B = *(const float4v*)(mub + base + 2 * D_);
        }

        const int j = it * 16 + js;
        const float m  = smsk[j];
        const float e0 = sdir[3 * j + 0];
        const float e1 = sdir[3 * j + 1];
        const float e2 = sdir[3 * j + 2];

        #pragma unroll
        for (int i = 0; i < 4; ++i) {
            aq[i] += wqA[i] * (xqA[i] * m);
            float tR = wRA[i] * (xRA[i] * m);
            float tm = wmA[i] * (xmA[i] * m);
            a0[i] += tR * e0 + tm * u0A[i];
            a1[i] += tR * e1 + tm * u1A[i];
            a2[i] += tR * e2 + tm * u2A[i];
        }

        wqA = wqB; wRA = wRB; wmA = wmB;
        xqA = xqB; xRA = xRB; xmA = xmB;
        u0A = u0B; u1A = u1B; u2A = u2B;
    }

    // fold the 4 j-slot groups within each wave (js differs in bits 4,5 of lane)
    #pragma unroll
    for (int i = 0; i < 4; ++i) {
        aq[i] += __shfl_xor(aq[i], 16, 64);
        aq[i] += __shfl_xor(aq[i], 32, 64);
        a0[i] += __shfl_xor(a0[i], 16, 64);
        a0[i] += __shfl_xor(a0[i], 32, 64);
        a1[i] += __shfl_xor(a1[i], 16, 64);
        a1[i] += __shfl_xor(a1[i], 32, 64);
        a2[i] += __shfl_xor(a2[i], 16, 64);
        a2[i] += __shfl_xor(a2[i], 32, 64);
    }

    // cross-wave reduction: ws[wave][quantity][64 ch]
    __shared__ __align__(16) float ws[4][4][64];
    const int w = t >> 6, l = t & 63;
    if (l < 16) {
        *(float4v*)&ws[w][0][4 * l] = aq;
        *(float4v*)&ws[w][1][4 * l] = a0;
        *(float4v*)&ws[w][2][4 * l] = a1;
        *(float4v*)&ws[w][3][4 * l] = a2;
    }
    __syncthreads();

    // epilogue: 256 outputs = 4 quantities x 64 channels, FP32 nt stores
    const int comp = t >> 6;       // 0 = dq, 1..3 = dmu components
    const int ch   = t & 63;
    float s = ws[0][comp][ch] + ws[1][comp][ch] + ws[2][comp][ch] + ws[3][comp][ch];

    if (comp == 0) {
        const size_t o = (size_t)bi * D_ + h * 64 + ch;
        __builtin_nontemporal_store(q[o] + s, out + o);
    } else {
        const size_t o = ((size_t)bi * 3 + (comp - 1)) * D_ + h * 64 + ch;
        __builtin_nontemporal_store(mu[o] + s, out + (size_t)(B_ * N_ * D_) + o);
    }
}

extern "C" void kernel_launch(void* const* d_in, const int* in_sizes, int n_in,
                              void* d_out, int out_size, void* d_ws, size_t ws_size,
                              hipStream_t stream) {
    const float* q     = (const float*)d_in[0];
    const float* mu    = (const float*)d_in[1];
    const float* Wij   = (const float*)d_in[2];
    const float* dir   = (const float*)d_in[3];
    const float* mask  = (const float*)d_in[4];
    const float* normw = (const float*)d_in[5];
    const float* W1    = (const float*)d_in[6];
    const float* b1    = (const float*)d_in[7];
    const float* W2    = (const float*)d_in[8];
    const float* b2    = (const float*)d_in[9];

    k1_mlp <<<B_ * N_,     256, 0, stream>>>(q, normw, W1, b1, W2, b2);
    k2_pair<<<B_ * N_ * 2, 256, 0, stream>>>(q, mu, Wij, dir, mask, (float*)d_out);
}

// Round 11
// 201.642 us; speedup vs baseline: 1.0103x; 1.0103x over previous
//
#include <hip/hip_runtime.h>

// World model (rounds 0-10): ALL inputs fp32, output fp32. Fixed harness work
// ~150-165 us of total. k2 plateau explained by vector-path BYTES: 3x compulsory
// (x/mu re-read per i). R11: 4-i-tile blocks amortize x/mu -> 1.5x compulsory.

#define B_ 4
#define N_ 128
#define D_ 128
#define I_ 4

typedef __attribute__((ext_vector_type(4))) float float4v;

// Static scratch: x = Dense2(GLU(Dense1(RMSNorm(q)))) as (B,N,3D) fp32.
__device__ __align__(16) float g_x[B_ * N_ * 3 * D_];

__device__ __forceinline__ float sigm(float x) { return 1.0f / (1.0f + __expf(-x)); }

// ---------------- Kernel 1: RMSNorm + GLU MLP -> g_x (R8 verbatim, proven) ------
__global__ __launch_bounds__(256) void k1_mlp(
        const float* __restrict__ q, const float* __restrict__ norm_w,
        const float* __restrict__ W1, const float* __restrict__ b1,
        const float* __restrict__ W2, const float* __restrict__ b2) {
    const int row = blockIdx.x;   // 0 .. B*N-1
    const int t   = threadIdx.x;  // 0 .. 255

    __shared__ __align__(16) float hbuf[D_];
    __shared__ __align__(16) float h2buf[D_];
    __shared__ float ybuf[2 * D_];
    __shared__ float red4[4];

    float v  = (t < D_) ? q[(size_t)row * D_ + t] : 0.0f;
    float ss = v * v;
    #pragma unroll
    for (int off = 32; off > 0; off >>= 1) ss += __shfl_down(ss, off);
    if ((t & 63) == 0) red4[t >> 6] = ss;
    __syncthreads();
    float var   = (red4[0] + red4[1] + red4[2] + red4[3]) * (1.0f / D_);
    float scale = rsqrtf(var + 1e-6f);
    if (t < D_) hbuf[t] = v * scale * (1.0f + norm_w[t]);
    __syncthreads();

    float y = b1[t];
    const float4v* wr = (const float4v*)(W1 + (size_t)t * D_);
    #pragma unroll 8
    for (int c = 0; c < D_ / 4; ++c) {
        float4v w4 = wr[c];
        float4v h4 = *(const float4v*)&hbuf[4 * c];
        y += w4.x * h4.x + w4.y * h4.y + w4.z * h4.z + w4.w * h4.w;
    }
    ybuf[t] = y;
    __syncthreads();
    if (t < D_) {
        float a = ybuf[t], g = ybuf[D_ + t];
        h2buf[t] = a * sigm(a) * sigm(g);
    }
    __syncthreads();

    float x0 = b2[t];
    float x1 = (t < D_) ? b2[2 * D_ + t] : 0.0f;
    const float4v* w0 = (const float4v*)(W2 + (size_t)t * D_);
    const float4v* w1 = (const float4v*)(W2 + (size_t)(2 * D_ + (t & (D_ - 1))) * D_);
    #pragma unroll 8
    for (int c = 0; c < D_ / 4; ++c) {
        float4v h4 = *(const float4v*)&h2buf[4 * c];
        float4v a4 = w0[c];
        x0 += a4.x * h4.x + a4.y * h4.y + a4.z * h4.z + a4.w * h4.w;
        if (t < D_) {
            float4v b4 = w1[c];
            x1 += b4.x * h4.x + b4.y * h4.y + b4.z * h4.z + b4.w * h4.w;
        }
    }
    float* xr = g_x + (size_t)row * (3 * D_);
    xr[t] = x0;
    if (t < D_) xr[2 * D_ + t] = x1;
}

// ---------------- Kernel 2: i-tiled pairwise reduce -----------------------------
// block = (b, i-tile of 4, channel-quarter cs of 32 ch); grid = 4*32*4 = 512.
// 256 threads = 8 channel-quads x 32 j-slots; 4 j-iterations.
// Per j-iteration: x/mu loaded ONCE (6 float4), Wij for 4 i's (12 nt float4)
// -> per-CU L1 traffic 151 MB (was 301 MB: x/mu re-read per i).
__global__ __launch_bounds__(256) void k2_pair(
        const float* __restrict__ q, const float* __restrict__ mu,
        const float* __restrict__ Wij, const float* __restrict__ dir,
        const float* __restrict__ mask, float* __restrict__ out) {
    const int blk = blockIdx.x;          // 0..511
    const int cs  = blk & 3;             // channel quarter
    const int ti  = (blk >> 2) & 31;     // i-tile index
    const int b   = blk >> 7;
    const int i0  = ti * I_;
    const int t   = threadIdx.x;         // 0..255
    const int quad = t & 7;              // channel quad within quarter
    const int js   = t >> 3;             // j-slot 0..31
    const int choff = cs * 32 + 4 * quad;

    const float* xb  = g_x + (size_t)b * (N_ * 3 * D_);
    const float* mub = mu  + (size_t)b * (N_ * 3 * D_);

    const float* Wb0 = Wij + (size_t)((b * N_ + i0 + 0) * N_) * (3 * D_);
    const float* Wb1 = Wij + (size_t)((b * N_ + i0 + 1) * N_) * (3 * D_);
    const float* Wb2 = Wij + (size_t)((b * N_ + i0 + 2) * N_) * (3 * D_);
    const float* Wb3 = Wij + (size_t)((b * N_ + i0 + 3) * N_) * (3 * D_);

    // stage mask/dir for the 4 i's (2 KB + 6 KB)
    __shared__ float smsk[I_][N_];
    __shared__ float sdir[I_][3 * N_];
    for (int idx = t; idx < I_ * N_; idx += 256) {
        const int ii = idx >> 7, j = idx & (N_ - 1);
        smsk[ii][j] = mask[(size_t)(b * N_ + i0 + ii) * N_ + j];
    }
    for (int idx = t; idx < I_ * 3 * N_; idx += 256) {
        const int ii = idx / (3 * N_), r = idx % (3 * N_);
        sdir[ii][r] = dir[(size_t)(b * N_ + i0 + ii) * (3 * N_) + r];
    }
    __syncthreads();

    float4v aq[I_], a0[I_], a1[I_], a2[I_];
    #pragma unroll
    for (int ii = 0; ii < I_; ++ii) {
        aq[ii] = {0.f, 0.f, 0.f, 0.f};
        a0[ii] = {0.f, 0.f, 0.f, 0.f};
        a1[ii] = {0.f, 0.f, 0.f, 0.f};
        a2[ii] = {0.f, 0.f, 0.f, 0.f};
    }

    #pragma unroll
    for (int jt = 0; jt < 4; ++jt) {
        const int j = jt * 32 + js;
        const size_t base = (size_t)j * (3 * D_) + choff;

        float4v xq = *(const float4v*)(xb + base);
        float4v xR = *(const float4v*)(xb + base + D_);
        float4v xm = *(const float4v*)(xb + base + 2 * D_);
        float4v u0 = *(const float4v*)(mub + base);
        float4v u1 = *(const float4v*)(mub + base + D_);
        float4v u2 = *(const float4v*)(mub + base + 2 * D_);

        #pragma unroll
        for (int ii = 0; ii < I_; ++ii) {
            const float* Wb = (ii == 0) ? Wb0 : (ii == 1) ? Wb1 : (ii == 2) ? Wb2 : Wb3;
            float4v wq = __builtin_nontemporal_load((const float4v*)(Wb + base));
            float4v wR = __builtin_nontemporal_load((const float4v*)(Wb + base + D_));
            float4v wm = __builtin_nontemporal_load((const float4v*)(Wb + base + 2 * D_));
            const float m  = smsk[ii][j];
            const float e0 = sdir[ii][3 * j + 0];
            const float e1 = sdir[ii][3 * j + 1];
            const float e2 = sdir[ii][3 * j + 2];
            #pragma unroll
            for (int c = 0; c < 4; ++c) {
                aq[ii][c] += wq[c] * (xq[c] * m);
                float tR = wR[c] * (xR[c] * m);
                float tm = wm[c] * (xm[c] * m);
                a0[ii][c] += tR * e0 + tm * u0[c];
                a1[ii][c] += tR * e1 + tm * u1[c];
                a2[ii][c] += tR * e2 + tm * u2[c];
            }
        }
    }

    // intra-wave fold over the 8 j-slots resident in this wave (lane bits 3,4,5)
    #pragma unroll
    for (int ii = 0; ii < I_; ++ii) {
        #pragma unroll
        for (int c = 0; c < 4; ++c) {
            aq[ii][c] += __shfl_xor(aq[ii][c], 8, 64);
            aq[ii][c] += __shfl_xor(aq[ii][c], 16, 64);
            aq[ii][c] += __shfl_xor(aq[ii][c], 32, 64);
            a0[ii][c] += __shfl_xor(a0[ii][c], 8, 64);
            a0[ii][c] += __shfl_xor(a0[ii][c], 16, 64);
            a0[ii][c] += __shfl_xor(a0[ii][c], 32, 64);
            a1[ii][c] += __shfl_xor(a1[ii][c], 8, 64);
            a1[ii][c] += __shfl_xor(a1[ii][c], 16, 64);
            a1[ii][c] += __shfl_xor(a1[ii][c], 32, 64);
            a2[ii][c] += __shfl_xor(a2[ii][c], 8, 64);
            a2[ii][c] += __shfl_xor(a2[ii][c], 16, 64);
            a2[ii][c] += __shfl_xor(a2[ii][c], 32, 64);
        }
    }

    // cross-wave reduce: red[wave][ii][qty][32 ch] = 8 KB
    __shared__ __align__(16) float red[4][I_][4][32];
    const int w = t >> 6, l = t & 63;
    if (l < 8) {   // representative lane per quad (quad == l)
        #pragma unroll
        for (int ii = 0; ii < I_; ++ii) {
            *(float4v*)&red[w][ii][0][4 * l] = aq[ii];
            *(float4v*)&red[w][ii][1][4 * l] = a0[ii];
            *(float4v*)&red[w][ii][2][4 * l] = a1[ii];
            *(float4v*)&red[w][ii][3][4 * l] = a2[ii];
        }
    }
    __syncthreads();

    // epilogue: 512 outputs = 4 qty x 4 ii x 32 ch; each thread stores 2.
    #pragma unroll
    for (int rep = 0; rep < 2; ++rep) {
        const int idx  = t + rep * 256;
        const int comp = idx >> 7;          // 0 = dq, 1..3 = dmu comp
        const int ii   = (idx >> 5) & 3;
        const int ch   = idx & 31;
        const float s = red[0][ii][comp][ch] + red[1][ii][comp][ch]
                      + red[2][ii][comp][ch] + red[3][ii][comp][ch];
        const int gi = b * N_ + i0 + ii;
        if (comp == 0) {
            const size_t o = (size_t)gi * D_ + cs * 32 + ch;
            __builtin_nontemporal_store(q[o] + s, out + o);
        } else {
            const size_t o = ((size_t)gi * 3 + (comp - 1)) * D_ + cs * 32 + ch;
            __builtin_nontemporal_store(mu[o] + s, out + (size_t)(B_ * N_ * D_) + o);
        }
    }
}

extern "C" void kernel_launch(void* const* d_in, const int* in_sizes, int n_in,
                              void* d_out, int out_size, void* d_ws, size_t ws_size,
                              hipStream_t stream) {
    const float* q     = (const float*)d_in[0];
    const float* mu    = (const float*)d_in[1];
    const float* Wij   = (const float*)d_in[2];
    const float* dir   = (const float*)d_in[3];
    const float* mask  = (const float*)d_in[4];
    const float* normw = (const float*)d_in[5];
    const float* W1    = (const float*)d_in[6];
    const float* b1    = (const float*)d_in[7];
    const float* W2    = (const float*)d_in[8];
    const float* b2    = (const float*)d_in[9];

    k1_mlp <<<B_ * N_,             256, 0, stream>>>(q, normw, W1, b1, W2, b2);
    k2_pair<<<B_ * (N_ / I_) * 4,  256, 0, stream>>>(q, mu, Wij, dir, mask,
                                                     (float*)d_out);
}